// Round 11
// baseline (3818.570 us; speedup 1.0000x reference)
//
#include <hip/hip_runtime.h>

typedef _Float16 h2_t __attribute__((ext_vector_type(2)));

#define HID  100
#define TENC 4096
#define TDEC 4096
#define NCLS 6
#define NTHR 512   // 8 waves, 2/SIMD: second wave's issue covers sync/DS/tail stalls

__device__ __forceinline__ float tanh_(float v) { return 1.0f - 2.0f * __builtin_amdgcn_rcpf(1.0f + __expf(2.0f * v)); }

// lgkm-only barrier (proven v8-v14): does NOT drain vmcnt.
#define SYNC_LDS() asm volatile("s_waitcnt lgkmcnt(0)\n\ts_barrier" ::: "memory")

__device__ __forceinline__ float packh2(float a, float b) {
    h2_t p; p[0] = (_Float16)a; p[1] = (_Float16)b;
    return __builtin_bit_cast(float, p);
}

__device__ __forceinline__ float fd2(float w, float h, float acc) {
    return __builtin_amdgcn_fdot2(__builtin_bit_cast(h2_t, w),
                                  __builtin_bit_cast(h2_t, h), acc, false);
}

// quad_perm [1,0,3,2] = 0xB1 (PROVEN v8/v14): exchange with xor-1 partner.
__device__ __forceinline__ float dppB1(float v) {
    return __builtin_bit_cast(float, __builtin_amdgcn_update_dpp(
        0, __builtin_bit_cast(int, v), 0xB1, 0xF, 0xF, true));
}
// quad_perm [2,3,0,1] = 0x4E (PROVEN v14): exchange with xor-2 partner.
__device__ __forceinline__ float dpp4E(float v) {
    return __builtin_bit_cast(float, __builtin_amdgcn_update_dpp(
        0, __builtin_bit_cast(int, v), 0x4E, 0xF, 0xF, true));
}
__device__ __forceinline__ float xsum1(float v) { return v + dppB1(v); }
__device__ __forceinline__ float xsum2(float v) { return v + dpp4E(v); }

// Persistent single-workgroup LSTM, v15 = v14 (PASSED, 3757us) with ONE
// variable changed: amdgpu_waves_per_eu(2,2) pins exactly 2 waves/EU ->
// 256-VGPR budget. v14's failure was VGPR_Count=64 vs ~85-90 live (3rd
// round lost to the occupancy heuristic: v11=84, v12=60, v14=64;
// __launch_bounds__(N,2) does NOT prevent it, amdgpu_waves_per_eu held 108
// in v13). With weights resident, per-wave issue ~230cy x 2 waves/SIMD
// interleaved covers the ds_read/barrier/tail stalls the 1-wave v8 exposed.
__global__ __launch_bounds__(NTHR) __attribute__((amdgpu_waves_per_eu(2, 2)))
void lstm_rec(const float* __restrict__ x,      // [TENC*3]
              const int*   __restrict__ y,      // [TDEC]
              const float* __restrict__ eWih,   // [400*3]
              const float* __restrict__ eWhh,   // [400*HID]
              const float* __restrict__ ebih,
              const float* __restrict__ ebhh,
              const float* __restrict__ dWih,   // [400]
              const float* __restrict__ dWhh,
              const float* __restrict__ dbih,
              const float* __restrict__ dbhh,
              float* __restrict__ hsto)         // [(TDEC-1)*HID] decoder h history
{
    __shared__ __align__(16) _Float16 hbuf[2][128];  // [parity][k-slot]: 0-99 h, 100-103 input, rest 0
    __shared__ __align__(8)  uint2    xst[TENC];     // packed f16: {x0,x1},{x2,1}
    __shared__               unsigned yst[TDEC];     // packed f16: {yf,0}

    const int  t    = threadIdx.x;
    const int  q    = t & 3;        // k-quarter / gate role (== DPP quad lane)
    const int  cell = t >> 2;       // 0..127 (100 live)
    const bool live = (cell < HID);
    const bool wq0  = live && (q == 0);   // h writer (and c owner)
    const bool wq1  = live && (q == 1);   // hsto writer (decoder)

    // activation constants: gate q -> q2 is tanh, others sigmoid
    const float cs = (q == 2) ?  2.0f : -1.0f;
    const float ms = (q == 2) ? -2.0f :  1.0f;
    const float as = (q == 2) ?  1.0f :  0.0f;

    // ---- stage x (f16 pairs) and y (f16) into LDS; zero h buffers ----
    for (int i = t; i < TENC; i += NTHR) {
        const float a = x[3*i], b = x[3*i+1], cc = x[3*i+2];
        uint2 u;
        u.x = __builtin_bit_cast(unsigned, packh2(a, b));
        u.y = __builtin_bit_cast(unsigned, packh2(cc, 1.0f));
        xst[i] = u;
    }
    for (int i = t; i < TDEC; i += NTHR)
        yst[i] = __builtin_bit_cast(unsigned, packh2((float)y[i], 0.0f));
    if (t < 256) ((_Float16*)hbuf)[t] = (_Float16)0.0f;   // both parities, 128 slots each
    __syncthreads();

    // x_0 into hbuf[0][100..103] (published by the SYNC_LDS below)
    if (t == 0) {
        uint2 u;
        u.x = __builtin_bit_cast(unsigned, packh2(x[0], x[1]));
        u.y = __builtin_bit_cast(unsigned, packh2(x[2], 1.0f));
        *(uint2*)&hbuf[0][100] = u;
    }

    // ---- encoder weights: wf[gate][13 pairs] over this lane's k-quarter ----
    // j<12: k = 8*(q+4*(j>>2)) + 2*(j&3)  (all <96 -> Whh)
    // j=12: k = 96+2q  (q0/q1: Whh 96..99; q2: Wih0,Wih1; q3: Wih2, bias)
    float wf[4][13];
    #pragma unroll
    for (int r = 0; r < 4; ++r) {
        const int row = r*HID + cell;
        #pragma unroll
        for (int j = 0; j < 12; ++j) {
            const int k = 8*(q + 4*(j >> 2)) + 2*(j & 3);
            float v0 = 0.0f, v1 = 0.0f;
            if (live) { v0 = eWhh[row*HID + k]; v1 = eWhh[row*HID + k + 1]; }
            wf[r][j] = packh2(v0, v1);
        }
        {
            const int k = 96 + 2*q;
            float v0 = 0.0f, v1 = 0.0f;
            if (live) {
                v0 = (k < HID) ? eWhh[row*HID + k] : eWih[row*3 + (k - 100)];
                v1 = (k + 1 < HID) ? eWhh[row*HID + k + 1]
                   : (k + 1 < 103) ? eWih[row*3 + (k + 1 - 100)]
                   : (ebih[row] + ebhh[row]);
            }
            wf[r][12] = packh2(v0, v1);
        }
    }
    SYNC_LDS();

    float c = 0.0f;
    int p = 0;

    // ================ encoder: 4096 steps ================
    for (int s = 0; s < TENC; ++s) {
        const _Float16* hb = hbuf[p];
        float hp[13];
        {   // 3x ds_read_b128 (element bases 8q, 8q+32, 8q+64) + 1x b32 (96+2q)
            const float4 g0 = *(const float4*)&hb[8*q];
            hp[0] = g0.x; hp[1] = g0.y; hp[2] = g0.z; hp[3] = g0.w;
            const float4 g1 = *(const float4*)&hb[8*q + 32];
            hp[4] = g1.x; hp[5] = g1.y; hp[6] = g1.z; hp[7] = g1.w;
            const float4 g2 = *(const float4*)&hb[8*q + 64];
            hp[8] = g2.x; hp[9] = g2.y; hp[10] = g2.z; hp[11] = g2.w;
            hp[12] = *(const float*)&hb[96 + 2*q];
        }

        if (t == 0 && s + 1 < TENC)                   // prefetch x_{s+1}
            *(uint2*)&hbuf[p ^ 1][100] = xst[s + 1];

        float p0 = 0.0f, p1 = 0.0f, p2 = 0.0f, p3 = 0.0f;
        #pragma unroll
        for (int j = 0; j < 13; ++j) {
            p0 = fd2(wf[0][j], hp[j], p0);
            p1 = fd2(wf[1][j], hp[j], p1);
            p2 = fd2(wf[2][j], hp[j], p2);
            p3 = fd2(wf[3][j], hp[j], p3);
        }
        const float a0 = xsum2(xsum1(p0));
        const float a1 = xsum2(xsum1(p1));
        const float a2 = xsum2(xsum1(p2));
        const float a3 = xsum2(xsum1(p3));

        // lane q activates gate q
        float u = a0;
        if (q == 1) u = a1;
        if (q == 2) u = a2;
        if (q == 3) u = a3;
        const float e   = __expf(u * cs);
        const float act = __builtin_fmaf(__builtin_amdgcn_rcpf(1.0f + e), ms, as);

        const float v1 = dppB1(act);   // q0 <- ff
        const float v2 = dpp4E(act);   // q0 <- fg
        const float v3 = dpp4E(v1);    // q0 <- fo
        c = __builtin_fmaf(v1, c, act * v2);   // valid on q0 only
        const float hn = v3 * tanh_(c);
        if (wq0)
            hbuf[p ^ 1][cell] = (_Float16)hn;
        SYNC_LDS();
        p ^= 1;
    }

    // ================ transition: decoder input slot {yf0, 1, 0, 0} ================
    if (t == 0) {
        uint2 v;
        v.x = (yst[0] & 0xFFFFu) | 0x3C000000u;   // {yf0, f16(1.0)}
        v.y = 0u;
        *(uint2*)&hbuf[p][100] = v;
    }

    // ---- decoder weights (reuse wf) ----
    #pragma unroll
    for (int r = 0; r < 4; ++r) {
        const int row = r*HID + cell;
        #pragma unroll
        for (int j = 0; j < 12; ++j) {
            const int k = 8*(q + 4*(j >> 2)) + 2*(j & 3);
            float v0 = 0.0f, v1 = 0.0f;
            if (live) { v0 = dWhh[row*HID + k]; v1 = dWhh[row*HID + k + 1]; }
            wf[r][j] = packh2(v0, v1);
        }
        {
            const int k = 96 + 2*q;
            float v0 = 0.0f, v1 = 0.0f;
            if (live) {
                v0 = (k < HID) ? dWhh[row*HID + k] : (k == 100) ? dWih[row] : 0.0f;
                v1 = (k + 1 < HID) ? dWhh[row*HID + k + 1]
                   : (k + 1 == 101) ? (dbih[row] + dbhh[row]) : 0.0f;
            }
            wf[r][12] = packh2(v0, v1);
        }
    }
    SYNC_LDS();

    // ================ decoder: 4095 steps (ratio==1 -> teacher-forced) ================
    for (int s = 0; s < TDEC - 1; ++s) {
        const _Float16* hb = hbuf[p];
        float hp[13];
        {
            const float4 g0 = *(const float4*)&hb[8*q];
            hp[0] = g0.x; hp[1] = g0.y; hp[2] = g0.z; hp[3] = g0.w;
            const float4 g1 = *(const float4*)&hb[8*q + 32];
            hp[4] = g1.x; hp[5] = g1.y; hp[6] = g1.z; hp[7] = g1.w;
            const float4 g2 = *(const float4*)&hb[8*q + 64];
            hp[8] = g2.x; hp[9] = g2.y; hp[10] = g2.z; hp[11] = g2.w;
            hp[12] = *(const float*)&hb[96 + 2*q];
        }

        if (t == 0 && s + 1 < TDEC - 1) {
            uint2 v;
            v.x = (yst[s + 1] & 0xFFFFu) | 0x3C000000u;
            v.y = 0u;
            *(uint2*)&hbuf[p ^ 1][100] = v;
        }

        float p0 = 0.0f, p1 = 0.0f, p2 = 0.0f, p3 = 0.0f;
        #pragma unroll
        for (int j = 0; j < 13; ++j) {
            p0 = fd2(wf[0][j], hp[j], p0);
            p1 = fd2(wf[1][j], hp[j], p1);
            p2 = fd2(wf[2][j], hp[j], p2);
            p3 = fd2(wf[3][j], hp[j], p3);
        }
        const float a0 = xsum2(xsum1(p0));
        const float a1 = xsum2(xsum1(p1));
        const float a2 = xsum2(xsum1(p2));
        const float a3 = xsum2(xsum1(p3));

        float u = a0;
        if (q == 1) u = a1;
        if (q == 2) u = a2;
        if (q == 3) u = a3;
        const float e   = __expf(u * cs);
        const float act = __builtin_fmaf(__builtin_amdgcn_rcpf(1.0f + e), ms, as);

        const float v1 = dppB1(act);
        const float v2 = dpp4E(act);
        const float v3 = dpp4E(v1);
        c = __builtin_fmaf(v1, c, act * v2);
        const float hn  = v3 * tanh_(c);
        const float hnb = dppB1(hn);          // q1 <- q0's hn
        if (wq0)
            hbuf[p ^ 1][cell] = (_Float16)hn;
        if (wq1)
            hsto[s * HID + cell] = hnb;       // global store, never fenced in-loop
        SYNC_LDS();
        p ^= 1;
    }
    // kernel end-of-dispatch drains the hsto stores before logits_k launches
}

// Parallel logits: out[t][r] = linW[r] . h_t + linb[r], last row zeroed.
__global__ __launch_bounds__(256)
void logits_k(const float* __restrict__ hsto, const float* __restrict__ linW,
              const float* __restrict__ linb, float* __restrict__ out)
{
    const int idx = blockIdx.x * 256 + threadIdx.x;
    if (idx >= TDEC * NCLS) return;
    const int tt = idx / NCLS;
    const int r  = idx % NCLS;
    if (tt >= TDEC - 1) { out[idx] = 0.0f; return; }
    const float* h  = hsto + tt * HID;
    const float* wr = linW + r * HID;
    float a = linb[r];
    #pragma unroll 4
    for (int k = 0; k < HID; ++k) a += wr[k] * h[k];
    out[idx] = a;
}

extern "C" void kernel_launch(void* const* d_in, const int* in_sizes, int n_in,
                              void* d_out, int out_size, void* d_ws, size_t ws_size,
                              hipStream_t stream)
{
    const float* x    = (const float*)d_in[0];
    const int*   y    = (const int*)  d_in[1];
    const float* eWih = (const float*)d_in[2];
    const float* eWhh = (const float*)d_in[3];
    const float* ebih = (const float*)d_in[4];
    const float* ebhh = (const float*)d_in[5];
    const float* dWih = (const float*)d_in[6];
    const float* dWhh = (const float*)d_in[7];
    const float* dbih = (const float*)d_in[8];
    const float* dbhh = (const float*)d_in[9];
    const float* linW = (const float*)d_in[10];
    const float* linb = (const float*)d_in[11];
    float* out  = (float*)d_out;
    float* hsto = (float*)d_ws;   // (TDEC-1)*HID*4 = 1.64 MB scratch

    lstm_rec<<<dim3(1), dim3(NTHR), 0, stream>>>(
        x, y, eWih, eWhh, ebih, ebhh, dWih, dWhh, dbih, dbhh, hsto);

    const int nout = TDEC * NCLS;
    logits_k<<<dim3((nout + 255) / 256), dim3(256), 0, stream>>>(hsto, linW, linb, out);
}

// Round 12
// 3674.203 us; speedup vs baseline: 1.0393x; 1.0393x over previous
//
#include <hip/hip_runtime.h>

typedef _Float16 h2_t __attribute__((ext_vector_type(2)));

#define HID  100
#define TENC 4096
#define TDEC 4096
#define NCLS 6
#define NTHR 256   // 4 waves, 1/SIMD: per-SIMD issue paid once (v14/v15 lesson)

__device__ __forceinline__ float sigm(float v)  { return __builtin_amdgcn_rcpf(1.0f + __expf(-v)); }
__device__ __forceinline__ float tanh_(float v) { return 1.0f - 2.0f * __builtin_amdgcn_rcpf(1.0f + __expf(2.0f * v)); }

// lgkm-only barrier (proven v8-v15): does NOT drain vmcnt.
#define SYNC_LDS() asm volatile("s_waitcnt lgkmcnt(0)\n\ts_barrier" ::: "memory")

__device__ __forceinline__ float packh2(float a, float b) {
    h2_t p; p[0] = (_Float16)a; p[1] = (_Float16)b;
    return __builtin_bit_cast(float, p);
}

__device__ __forceinline__ float fd2(float w, float h, float acc) {
    return __builtin_amdgcn_fdot2(__builtin_bit_cast(h2_t, w),
                                  __builtin_bit_cast(h2_t, h), acc, false);
}

// quad_perm [1,0,3,2] = 0xB1 (PROVEN v8/v14/v15): exchange with xor-1 partner.
__device__ __forceinline__ float dppB1(float v) {
    return __builtin_bit_cast(float, __builtin_amdgcn_update_dpp(
        0, __builtin_bit_cast(int, v), 0xB1, 0xF, 0xF, true));
}
__device__ __forceinline__ float xsum1(float v) { return v + dppB1(v); }

// Persistent single-workgroup LSTM, v16 = v8 (champion, 3414us) minus its
// measured issue overhead. v15 closed the TLP arc: per-SIMD issue is the
// currency (v8: 640cy = 416 MAC + 224 ovh; step 1000 = issue + ~360 stall).
// Changes vs v8 (primitives all proven):
//  1. x/bias folded into k-slots 100..103 (v10-v15 staging): k-split
//     lo=0..51 / hi=52..103, 26 pairs each — removes the 8-fdot2 x-part and
//     wxp/bs regs. h lives in two PADDED half-rows hbuf2[par][half][56]
//     (112B stride, 16B-aligned) so ds_read_b128 stays legal; x at
//     half1 slots 48..51.
//  2. activation split across the xor-1 pair via dppB1: lo computes
//     i=sigm(a0), g=tanh(a2); hi computes f=sigm(a1), o=sigm(a3)
//     (shared-exp const form, proven v14); 2 exchanges + 4 cndmask give
//     both lanes all 4 gates. 10 trans/lane -> 6.
//  3. amdgpu_waves_per_eu(1,1) pins the VGPR budget (v13 evidence).
__global__ __launch_bounds__(NTHR, 1) __attribute__((amdgpu_waves_per_eu(1, 1)))
void lstm_rec(const float* __restrict__ x,      // [TENC*3]
              const int*   __restrict__ y,      // [TDEC]
              const float* __restrict__ eWih,   // [400*3]
              const float* __restrict__ eWhh,   // [400*HID]
              const float* __restrict__ ebih,
              const float* __restrict__ ebhh,
              const float* __restrict__ dWih,   // [400]
              const float* __restrict__ dWhh,
              const float* __restrict__ dbih,
              const float* __restrict__ dbhh,
              float* __restrict__ hsto)         // [(TDEC-1)*HID] decoder h history
{
    // [parity][k-half][56]: half0 slots 0..51 = k 0..51; half1 slots 0..47 =
    // k 52..99, slots 48..51 = k 100..103 (input+bias "1"); 52..55 pad=0.
    __shared__ __align__(16) _Float16 hbuf2[2][2][56];
    __shared__ __align__(8)  uint2    xst[TENC];     // packed f16: {x0,x1},{x2,1}
    __shared__               unsigned yst[TDEC];     // packed f16: {yf,0}

    const int  t     = threadIdx.x;
    const int  w     = t >> 6;
    const int  l     = t & 63;
    const int  khalf = l & 1;           // k-half on ADJACENT lanes (dppB1-reachable)
    const int  cell  = w * 32 + (l >> 1);
    const bool live  = (cell < HID);

    // shared-exp activation constants for rB: lo -> tanh(g), hi -> sigm(o)
    const float cs = (khalf == 0) ?  2.0f : -1.0f;
    const float ms = (khalf == 0) ? -2.0f :  1.0f;
    const float as = (khalf == 0) ?  1.0f :  0.0f;

    // ---- stage x (f16 pairs) and y (f16) into LDS; zero h buffers ----
    for (int i = t; i < TENC; i += NTHR) {
        const float a = x[3*i], b = x[3*i+1], cc = x[3*i+2];
        uint2 u;
        u.x = __builtin_bit_cast(unsigned, packh2(a, b));
        u.y = __builtin_bit_cast(unsigned, packh2(cc, 1.0f));
        xst[i] = u;
    }
    for (int i = t; i < TDEC; i += NTHR)
        yst[i] = __builtin_bit_cast(unsigned, packh2((float)y[i], 0.0f));
    if (t < 2*2*56) ((_Float16*)hbuf2)[t] = (_Float16)0.0f;
    __syncthreads();

    // x_0 into half1 slots 48..51 of parity 0 (published by SYNC_LDS below)
    if (t == 0) {
        uint2 u;
        u.x = __builtin_bit_cast(unsigned, packh2(x[0], x[1]));
        u.y = __builtin_bit_cast(unsigned, packh2(x[2], 1.0f));
        *(uint2*)&hbuf2[0][1][48] = u;
    }

    // ---- encoder weights: wf[gate][26 pairs], k = 52*khalf + 2j ----
    float wf[4][26];
    #pragma unroll
    for (int r = 0; r < 4; ++r) {
        const int row = r*HID + cell;
        #pragma unroll
        for (int j = 0; j < 26; ++j) {
            const int k0 = 52*khalf + 2*j, k1 = k0 + 1;
            float v0 = 0.0f, v1 = 0.0f;
            if (live) {
                v0 = (k0 < HID) ? eWhh[row*HID + k0]
                   : (k0 < 103) ? eWih[row*3 + (k0 - 100)] : (ebih[row] + ebhh[row]);
                v1 = (k1 < HID) ? eWhh[row*HID + k1]
                   : (k1 < 103) ? eWih[row*3 + (k1 - 100)] : (ebih[row] + ebhh[row]);
            }
            wf[r][j] = packh2(v0, v1);
        }
    }
    SYNC_LDS();

    // hoisted h-write slot (cell fixed per lane)
    const int hh2  = (cell < 52) ? 0 : 1;
    const int hoff = cell - 52*hh2;

    float c = 0.0f;
    int p = 0;

    // ================ encoder: 4096 steps ================
    for (int s = 0; s < TENC; ++s) {
        const _Float16* hr = &hbuf2[p][khalf][0];
        float hp[26];
        {   // 6x ds_read_b128 + 1x ds_read_b64, all 16B/8B aligned
            const float4 g0 = *(const float4*)&hr[0];
            const float4 g1 = *(const float4*)&hr[8];
            const float4 g2 = *(const float4*)&hr[16];
            const float4 g3 = *(const float4*)&hr[24];
            const float4 g4 = *(const float4*)&hr[32];
            const float4 g5 = *(const float4*)&hr[40];
            const float2 g6 = *(const float2*)&hr[48];
            hp[0]=g0.x; hp[1]=g0.y; hp[2]=g0.z; hp[3]=g0.w;
            hp[4]=g1.x; hp[5]=g1.y; hp[6]=g1.z; hp[7]=g1.w;
            hp[8]=g2.x; hp[9]=g2.y; hp[10]=g2.z; hp[11]=g2.w;
            hp[12]=g3.x; hp[13]=g3.y; hp[14]=g3.z; hp[15]=g3.w;
            hp[16]=g4.x; hp[17]=g4.y; hp[18]=g4.z; hp[19]=g4.w;
            hp[20]=g5.x; hp[21]=g5.y; hp[22]=g5.z; hp[23]=g5.w;
            hp[24]=g6.x; hp[25]=g6.y;
        }

        if (t == 0 && s + 1 < TENC)                   // prefetch x_{s+1}
            *(uint2*)&hbuf2[p ^ 1][1][48] = xst[s + 1];

        float a0 = 0.0f, a1 = 0.0f, a2 = 0.0f, a3 = 0.0f;
        #pragma unroll
        for (int j = 0; j < 26; ++j) {
            a0 = fd2(wf[0][j], hp[j], a0);
            a1 = fd2(wf[1][j], hp[j], a1);
            a2 = fd2(wf[2][j], hp[j], a2);
            a3 = fd2(wf[3][j], hp[j], a3);
        }
        a0 = xsum1(a0);
        a1 = xsum1(a1);
        a2 = xsum1(a2);
        a3 = xsum1(a3);

        // split activations: lo does i=sigm(a0), g=tanh(a2); hi does f=sigm(a1), o=sigm(a3)
        const float uA = khalf ? a1 : a0;
        const float rA = sigm(uA);                     // lo: i, hi: f
        const float uB = khalf ? a3 : a2;
        const float eB = __expf(uB * cs);
        const float rB = __builtin_fmaf(__builtin_amdgcn_rcpf(1.0f + eB), ms, as); // lo: g, hi: o
        const float sA = dppB1(rA);                    // lo: f, hi: i
        const float sB = dppB1(rB);                    // lo: o, hi: g
        const float fi = khalf ? sA : rA;
        const float ff = khalf ? rA : sA;
        const float fg = khalf ? sB : rB;
        const float fo = khalf ? rB : sB;

        c = __builtin_fmaf(ff, c, fi * fg);            // replicated in both pair lanes
        const float hn = fo * tanh_(c);
        if (khalf == 0 && live)
            hbuf2[p ^ 1][hh2][hoff] = (_Float16)hn;
        SYNC_LDS();
        p ^= 1;
    }

    // ================ transition: decoder input slots {yf0, 1, 0, 0} ================
    if (t == 0) {
        uint2 v;
        v.x = (yst[0] & 0xFFFFu) | 0x3C000000u;   // {yf0, f16(1.0)}
        v.y = 0u;
        *(uint2*)&hbuf2[p][1][48] = v;
    }

    // ---- decoder weights (reuse wf) ----
    #pragma unroll
    for (int r = 0; r < 4; ++r) {
        const int row = r*HID + cell;
        #pragma unroll
        for (int j = 0; j < 26; ++j) {
            const int k0 = 52*khalf + 2*j, k1 = k0 + 1;
            float v0 = 0.0f, v1 = 0.0f;
            if (live) {
                v0 = (k0 < HID) ? dWhh[row*HID + k0]
                   : (k0 == 100) ? dWih[row]
                   : (k0 == 101) ? (dbih[row] + dbhh[row]) : 0.0f;
                v1 = (k1 < HID) ? dWhh[row*HID + k1]
                   : (k1 == 100) ? dWih[row]
                   : (k1 == 101) ? (dbih[row] + dbhh[row]) : 0.0f;
            }
            wf[r][j] = packh2(v0, v1);
        }
    }
    SYNC_LDS();

    // ================ decoder: 4095 steps (ratio==1 -> teacher-forced) ================
    for (int s = 0; s < TDEC - 1; ++s) {
        const _Float16* hr = &hbuf2[p][khalf][0];
        float hp[26];
        {
            const float4 g0 = *(const float4*)&hr[0];
            const float4 g1 = *(const float4*)&hr[8];
            const float4 g2 = *(const float4*)&hr[16];
            const float4 g3 = *(const float4*)&hr[24];
            const float4 g4 = *(const float4*)&hr[32];
            const float4 g5 = *(const float4*)&hr[40];
            const float2 g6 = *(const float2*)&hr[48];
            hp[0]=g0.x; hp[1]=g0.y; hp[2]=g0.z; hp[3]=g0.w;
            hp[4]=g1.x; hp[5]=g1.y; hp[6]=g1.z; hp[7]=g1.w;
            hp[8]=g2.x; hp[9]=g2.y; hp[10]=g2.z; hp[11]=g2.w;
            hp[12]=g3.x; hp[13]=g3.y; hp[14]=g3.z; hp[15]=g3.w;
            hp[16]=g4.x; hp[17]=g4.y; hp[18]=g4.z; hp[19]=g4.w;
            hp[20]=g5.x; hp[21]=g5.y; hp[22]=g5.z; hp[23]=g5.w;
            hp[24]=g6.x; hp[25]=g6.y;
        }

        if (t == 0 && s + 1 < TDEC - 1) {
            uint2 v;
            v.x = (yst[s + 1] & 0xFFFFu) | 0x3C000000u;
            v.y = 0u;
            *(uint2*)&hbuf2[p ^ 1][1][48] = v;
        }

        float a0 = 0.0f, a1 = 0.0f, a2 = 0.0f, a3 = 0.0f;
        #pragma unroll
        for (int j = 0; j < 26; ++j) {
            a0 = fd2(wf[0][j], hp[j], a0);
            a1 = fd2(wf[1][j], hp[j], a1);
            a2 = fd2(wf[2][j], hp[j], a2);
            a3 = fd2(wf[3][j], hp[j], a3);
        }
        a0 = xsum1(a0);
        a1 = xsum1(a1);
        a2 = xsum1(a2);
        a3 = xsum1(a3);

        const float uA = khalf ? a1 : a0;
        const float rA = sigm(uA);
        const float uB = khalf ? a3 : a2;
        const float eB = __expf(uB * cs);
        const float rB = __builtin_fmaf(__builtin_amdgcn_rcpf(1.0f + eB), ms, as);
        const float sA = dppB1(rA);
        const float sB = dppB1(rB);
        const float fi = khalf ? sA : rA;
        const float ff = khalf ? rA : sA;
        const float fg = khalf ? sB : rB;
        const float fo = khalf ? rB : sB;

        c = __builtin_fmaf(ff, c, fi * fg);
        const float hn = fo * tanh_(c);
        if (live) {
            if (khalf == 0) {
                hbuf2[p ^ 1][hh2][hoff] = (_Float16)hn;
            } else {
                hsto[s * HID + cell] = hn;     // global store, never fenced in-loop
            }
        }
        SYNC_LDS();
        p ^= 1;
    }
    // kernel end-of-dispatch drains the hsto stores before logits_k launches
}

// Parallel logits: out[t][r] = linW[r] . h_t + linb[r], last row zeroed.
__global__ __launch_bounds__(256)
void logits_k(const float* __restrict__ hsto, const float* __restrict__ linW,
              const float* __restrict__ linb, float* __restrict__ out)
{
    const int idx = blockIdx.x * 256 + threadIdx.x;
    if (idx >= TDEC * NCLS) return;
    const int tt = idx / NCLS;
    const int r  = idx % NCLS;
    if (tt >= TDEC - 1) { out[idx] = 0.0f; return; }
    const float* h  = hsto + tt * HID;
    const float* wr = linW + r * HID;
    float a = linb[r];
    #pragma unroll 4
    for (int k = 0; k < HID; ++k) a += wr[k] * h[k];
    out[idx] = a;
}

extern "C" void kernel_launch(void* const* d_in, const int* in_sizes, int n_in,
                              void* d_out, int out_size, void* d_ws, size_t ws_size,
                              hipStream_t stream)
{
    const float* x    = (const float*)d_in[0];
    const int*   y    = (const int*)  d_in[1];
    const float* eWih = (const float*)d_in[2];
    const float* eWhh = (const float*)d_in[3];
    const float* ebih = (const float*)d_in[4];
    const float* ebhh = (const float*)d_in[5];
    const float* dWih = (const float*)d_in[6];
    const float* dWhh = (const float*)d_in[7];
    const float* dbih = (const float*)d_in[8];
    const float* dbhh = (const float*)d_in[9];
    const float* linW = (const float*)d_in[10];
    const float* linb = (const float*)d_in[11];
    float* out  = (float*)d_out;
    float* hsto = (float*)d_ws;   // (TDEC-1)*HID*4 = 1.64 MB scratch

    lstm_rec<<<dim3(1), dim3(NTHR), 0, stream>>>(
        x, y, eWih, eWhh, ebih, ebhh, dWih, dWhh, dbih, dbhh, hsto);

    const int nout = TDEC * NCLS;
    logits_k<<<dim3((nout + 255) / 256), dim3(256), 0, stream>>>(hsto, linW, linb, out);
}